// Round 9
// baseline (49493.686 us; speedup 1.0000x reference)
//
#include <hip/hip_runtime.h>
#include <cstdint>
#include <cstddef>

#define TINYF 1.17549435e-38f
#define ROWS 8

// ---------------- static device workspace ----------------
// packed streamed weights: [gate][k4][j] float4 = W[goff+j][4k4..4k4+3]
// padded +512 so the software-pipeline prefetch at k4=127 stays in bounds.
__device__ __align__(256) float4 g_pw0[3 * 65536 + 512];   // whh0 (cell0 h-side)
__device__ __align__(256) float4 g_pwx[3 * 65536 + 512];   // wih1 (cell1 x-side)
__device__ __align__(256) float4 g_pwh[3 * 65536 + 512];   // whh1 (cell1 h-side)
__device__ __align__(256) float4 g_plo[65536 + 512];       // out_w (logits)

__device__ __align__(256) float g_wih0T[512 * 2048];   // [tok][gate_row] one-hot gather
__device__ __align__(256) float g_pew1T[1024 * 512];
__device__ __align__(256) float g_pew2T[512 * 256];
__device__ __align__(256) float g_fcwT[384 * 512];
__device__ __align__(256) float g_pe1[4096 * 512];
__device__ __align__(256) float g_pe2[4096 * 256];
__device__ __align__(256) float g_h0[4096 * 512];

__device__ __forceinline__ float* sel_wt(int s) {
  switch (s) {
    case 0: return g_wih0T; case 5: return g_pew1T;
    case 6: return g_pew2T; case 7: return g_fcwT;
    default: return nullptr;
  }
}
__device__ __forceinline__ float4* sel_pack(int s) {
  switch (s) {
    case 0: return g_pw0; case 1: return g_pwx;
    case 2: return g_pwh; case 3: return g_plo;
    default: return nullptr;
  }
}

// ---------------- JAX threefry2x32 (bit-exact) ----------------
__device__ __forceinline__ uint32_t rotl32(uint32_t v, int d) {
  return (v << d) | (v >> (32 - d));
}
__device__ __forceinline__ void threefry2x32(uint32_t k0, uint32_t k1,
                                             uint32_t x0, uint32_t x1,
                                             uint32_t& o0, uint32_t& o1) {
  uint32_t k2 = k0 ^ k1 ^ 0x1BD11BDAu;
#define TF_ROUND(d) { x0 += x1; x1 = rotl32(x1, (d)); x1 ^= x0; }
  x0 += k0; x1 += k1;
  TF_ROUND(13) TF_ROUND(15) TF_ROUND(26) TF_ROUND(6)
  x0 += k1; x1 += k2 + 1u;
  TF_ROUND(17) TF_ROUND(29) TF_ROUND(16) TF_ROUND(24)
  x0 += k2; x1 += k0 + 2u;
  TF_ROUND(13) TF_ROUND(15) TF_ROUND(26) TF_ROUND(6)
  x0 += k0; x1 += k1 + 3u;
  TF_ROUND(17) TF_ROUND(29) TF_ROUND(16) TF_ROUND(24)
  x0 += k1; x1 += k2 + 4u;
  TF_ROUND(13) TF_ROUND(15) TF_ROUND(26) TF_ROUND(6)
  x0 += k2; x1 += k0 + 5u;
#undef TF_ROUND
  o0 = x0; o1 = x1;
}

// partitionable random_bits (32-bit): bits = o0 ^ o1 of TF(key, (0, flat_idx))
__device__ __forceinline__ float gumbel_from_bits(uint32_t bits) {
  float f = __uint_as_float((bits >> 9) | 0x3f800000u) - 1.0f;  // [0,1)
  float u = fmaxf(TINYF, __fadd_rn(f, TINYF));
  return -logf(-logf(u));
}

// XLA-style f32 tanh rational approx.
__device__ __forceinline__ float xla_tanh(float x) {
  float ax = fabsf(x);
  float xc = fminf(fmaxf(x, -7.90531110763549805f), 7.90531110763549805f);
  float x2 = __fmul_rn(xc, xc);
  float p = -2.76076847742355e-16f;
  p = __fadd_rn(__fmul_rn(p, x2), 2.00018790482477e-13f);
  p = __fadd_rn(__fmul_rn(p, x2), -8.60467152213735e-11f);
  p = __fadd_rn(__fmul_rn(p, x2), 5.12229709037114e-08f);
  p = __fadd_rn(__fmul_rn(p, x2), 1.48572235717979e-05f);
  p = __fadd_rn(__fmul_rn(p, x2), 6.37261928875436e-04f);
  p = __fadd_rn(__fmul_rn(p, x2), 4.89352455891786e-03f);
  p = __fmul_rn(p, xc);
  float q = 1.19825839466702e-06f;
  q = __fadd_rn(__fmul_rn(q, x2), 1.18534705686654e-04f);
  q = __fadd_rn(__fmul_rn(q, x2), 2.26843463243900e-03f);
  q = __fadd_rn(__fmul_rn(q, x2), 4.89352518554385e-03f);
  float r = __fdiv_rn(p, q);
  return (ax < 0.0004f) ? x : r;
}
__device__ __forceinline__ float xla_sigmoid(float x) {
  return __fdiv_rn(1.0f, __fadd_rn(1.0f, expf(-x)));
}

// fma of a float4 pair into a scalar accumulator, ascending component order
// (x,y,z,w == ascending k) — bit-identical to the scalar fmaf chain.
__device__ __forceinline__ float fma4(float acc, const float4& a, const float4& b) {
  acc = __builtin_fmaf(a.x, b.x, acc);
  acc = __builtin_fmaf(a.y, b.y, acc);
  acc = __builtin_fmaf(a.z, b.z, acc);
  acc = __builtin_fmaf(a.w, b.w, acc);
  return acc;
}

// ---------------- setup: transpose + pack ----------------
// in [R][C] row-major -> out[c*R + r]
__global__ __launch_bounds__(256) void transpose_any(const float* __restrict__ in,
                                                     int R, int C, int wt_sel) {
  float* out = sel_wt(wt_sel);
  __shared__ float tile[32][33];
  const int c0 = blockIdx.x * 32, r0 = blockIdx.y * 32;
  const int tx = threadIdx.x & 31, ty = threadIdx.x >> 5;
#pragma unroll
  for (int i = 0; i < 32; i += 8)
    tile[ty + i][tx] = in[(size_t)(r0 + ty + i) * C + c0 + tx];
  __syncthreads();
#pragma unroll
  for (int i = 0; i < 32; i += 8)
    out[(size_t)(c0 + ty + i) * R + r0 + tx] = tile[tx][ty + i];
}

// pack gates i,g,o of a [2048][512] matrix: dst[g*65536 + k4*512 + j] =
// float4(src[goff[g]+j][4k4 .. 4k4+3])
__global__ __launch_bounds__(256) void pack3_kernel(const float* __restrict__ src,
                                                    int dst_sel) {
  const int id = blockIdx.x * 256 + threadIdx.x;      // 196608 total
  const int g = id >> 16;
  const int rem = id & 65535;
  const int k4 = rem >> 9, j = rem & 511;
  const int goff[3] = {0, 1024, 1536};
  const float4 v = *(const float4*)&src[(size_t)(goff[g] + j) * 512 + k4 * 4];
  sel_pack(dst_sel)[id] = v;
}

// pack out_w [512][512]: dst[k4*512 + j] = float4(src[j][4k4 .. 4k4+3])
__global__ __launch_bounds__(256) void pack1_kernel(const float* __restrict__ src,
                                                    int dst_sel) {
  const int id = blockIdx.x * 256 + threadIdx.x;      // 65536 total
  const int k4 = id >> 9, j = id & 511;
  const float4 v = *(const float4*)&src[(size_t)j * 512 + k4 * 4];
  sel_pack(dst_sel)[id] = v;
}

// ---------------- prefix: pe1, pe2, h0 ----------------
__global__ __launch_bounds__(512) void pe1_kernel(const float* __restrict__ P,
                                                  const float* __restrict__ b1) {
  __shared__ float a[1024];
  const int b = blockIdx.x, j = threadIdx.x;
  a[j] = P[(size_t)b * 1024 + j];
  a[j + 512] = P[(size_t)b * 1024 + j + 512];
  __syncthreads();
  float acc = 0.0f;
  for (int k = 0; k < 1024; ++k) acc += g_pew1T[(size_t)k * 512 + j] * a[k];
  g_pe1[(size_t)b * 512 + j] = fmaxf(__fadd_rn(acc, b1[j]), 0.0f);
}

__global__ __launch_bounds__(256) void pe2_kernel(const float* __restrict__ b2) {
  __shared__ float a[512];
  const int b = blockIdx.x, j = threadIdx.x;
  a[j] = g_pe1[(size_t)b * 512 + j];
  a[j + 256] = g_pe1[(size_t)b * 512 + j + 256];
  __syncthreads();
  float acc = 0.0f;
  for (int k = 0; k < 512; ++k) acc += g_pew2T[(size_t)k * 256 + j] * a[k];
  g_pe2[(size_t)b * 256 + j] = fmaxf(__fadd_rn(acc, b2[j]), 0.0f);
}

__global__ __launch_bounds__(512) void h0_kernel(const float* __restrict__ z,
                                                 const float* __restrict__ fcb) {
  __shared__ float a[384];
  const int b = blockIdx.x, j = threadIdx.x;
  if (j < 128) a[j] = z[(size_t)b * 128 + j];
  if (j < 256) a[128 + j] = g_pe2[(size_t)b * 256 + j];
  __syncthreads();
  float acc = 0.0f;
  for (int k = 0; k < 384; ++k) acc += g_fcwT[(size_t)k * 512 + j] * a[k];
  g_h0[(size_t)b * 512 + j] = __fadd_rn(acc, fcb[j]);
}

// ---------------- fused 100-step recurrence ----------------
// Same math as round 7 (identical fmaf chains in ascending k), with
// float4-packed weight streams, explicit b128 LDS reads, and a one-deep
// software pipeline on the weight loads.
__global__ __launch_bounds__(512) void rnn_kernel(
    const float* __restrict__ bih0, const float* __restrict__ bhh0,
    const float* __restrict__ bih1, const float* __restrict__ bhh1,
    const float* __restrict__ outb, int* __restrict__ out) {
  __shared__ float sha[ROWS][512];
  __shared__ float shb[ROWS][512];
  __shared__ float sx[ROWS][512];
  __shared__ int stok[ROWS];

  const int j = threadIdx.x;
  const int b0 = blockIdx.x * ROWS;

  const float bc0i = __fadd_rn(bih0[j],        bhh0[j]);
  const float bc0g = __fadd_rn(bih0[1024 + j], bhh0[1024 + j]);
  const float bc0o = __fadd_rn(bih0[1536 + j], bhh0[1536 + j]);
  const float bc1i = __fadd_rn(bih1[j],        bhh1[j]);
  const float bc1g = __fadd_rn(bih1[1024 + j], bhh1[1024 + j]);
  const float bc1o = __fadd_rn(bih1[1536 + j], bhh1[1536 + j]);
  const float ob   = outb[j];

#pragma unroll
  for (int r = 0; r < ROWS; ++r) {
    const float h0 = g_h0[(size_t)(b0 + r) * 512 + j];
    sha[r][j] = h0;
    shb[r][j] = h0;
  }
  if (j < ROWS) stok[j] = 511;
  __syncthreads();

  for (int t = 0; t < 100; ++t) {
    uint32_t k0, k1;
    threefry2x32(0u, 1u, 0u, (uint32_t)t, k0, k1);   // keys[t] (partitionable)

    // ---- cell0 h-term: ha @ whh0^T (gates i,g,o; f dead) ----
    {
      float ai[ROWS], ag[ROWS], ao[ROWS];
#pragma unroll
      for (int r = 0; r < ROWS; ++r) { ai[r] = 0.0f; ag[r] = 0.0f; ao[r] = 0.0f; }
      const float4* Wi = g_pw0 + j;
      const float4* Wg = g_pw0 + 65536 + j;
      const float4* Wo = g_pw0 + 131072 + j;
      float4 wi = Wi[0], wg = Wg[0], wo = Wo[0];
#pragma unroll 1
      for (int k4 = 0; k4 < 128; ++k4) {
        const int nx = (k4 + 1) * 512;
        const float4 wi_n = Wi[nx], wg_n = Wg[nx], wo_n = Wo[nx];  // padded
#pragma unroll
        for (int r = 0; r < ROWS; ++r) {
          const float4 hv = *(const float4*)&sha[r][k4 * 4];
          ai[r] = fma4(ai[r], wi, hv);
          ag[r] = fma4(ag[r], wg, hv);
          ao[r] = fma4(ao[r], wo, hv);
        }
        wi = wi_n; wg = wg_n; wo = wo_n;
      }
      __syncthreads();                    // all reads of sha complete
#pragma unroll
      for (int r = 0; r < ROWS; ++r) {
        const float* xr = g_wih0T + (size_t)stok[r] * 2048;  // exact one-hot x-term
        const float iv = __fadd_rn(__fadd_rn(xr[j],        ai[r]), bc0i);
        const float gv = __fadd_rn(__fadd_rn(xr[1024 + j], ag[r]), bc0g);
        const float ov = __fadd_rn(__fadd_rn(xr[1536 + j], ao[r]), bc0o);
        const float c = __fmul_rn(xla_sigmoid(iv), xla_tanh(gv));
        sha[r][j] = __fmul_rn(xla_sigmoid(ov), xla_tanh(c));
      }
      __syncthreads();                    // sha now holds ha'
    }

    // ---- cell1: ha' @ wih1^T + hb @ whh1^T ----
    {
      float xi[ROWS], xg[ROWS], xo[ROWS], hi[ROWS], hg[ROWS], ho[ROWS];
#pragma unroll
      for (int r = 0; r < ROWS; ++r) {
        xi[r] = 0.0f; xg[r] = 0.0f; xo[r] = 0.0f;
        hi[r] = 0.0f; hg[r] = 0.0f; ho[r] = 0.0f;
      }
      const float4* Xi = g_pwx + j;
      const float4* Xg = g_pwx + 65536 + j;
      const float4* Xo = g_pwx + 131072 + j;
      const float4* Hi = g_pwh + j;
      const float4* Hg = g_pwh + 65536 + j;
      const float4* Ho = g_pwh + 131072 + j;
      float4 wxi = Xi[0], wxg = Xg[0], wxo = Xo[0];
      float4 whi = Hi[0], whg = Hg[0], who = Ho[0];
#pragma unroll 1
      for (int k4 = 0; k4 < 128; ++k4) {
        const int nx = (k4 + 1) * 512;
        const float4 wxi_n = Xi[nx], wxg_n = Xg[nx], wxo_n = Xo[nx];
        const float4 whi_n = Hi[nx], whg_n = Hg[nx], who_n = Ho[nx];
#pragma unroll
        for (int r = 0; r < ROWS; ++r) {
          const float4 xv = *(const float4*)&sha[r][k4 * 4];
          const float4 hv = *(const float4*)&shb[r][k4 * 4];
          xi[r] = fma4(xi[r], wxi, xv);
          xg[r] = fma4(xg[r], wxg, xv);
          xo[r] = fma4(xo[r], wxo, xv);
          hi[r] = fma4(hi[r], whi, hv);
          hg[r] = fma4(hg[r], whg, hv);
          ho[r] = fma4(ho[r], who, hv);
        }
        wxi = wxi_n; wxg = wxg_n; wxo = wxo_n;
        whi = whi_n; whg = whg_n; who = who_n;
      }
      __syncthreads();                    // all reads of shb complete
#pragma unroll
      for (int r = 0; r < ROWS; ++r) {
        const float iv = __fadd_rn(__fadd_rn(xi[r], hi[r]), bc1i);
        const float gv = __fadd_rn(__fadd_rn(xg[r], hg[r]), bc1g);
        const float ov = __fadd_rn(__fadd_rn(xo[r], ho[r]), bc1o);
        const float c = __fmul_rn(xla_sigmoid(iv), xla_tanh(gv));
        shb[r][j] = __fmul_rn(xla_sigmoid(ov), xla_tanh(c));
      }
      __syncthreads();                    // shb now holds hb'
    }

    // ---- logits + gumbel ----
    {
      float lg[ROWS];
#pragma unroll
      for (int r = 0; r < ROWS; ++r) lg[r] = 0.0f;
      const float4* Wl = g_plo + j;
      float4 wl = Wl[0];
#pragma unroll 1
      for (int k4 = 0; k4 < 128; ++k4) {
        const float4 wl_n = Wl[(k4 + 1) * 512];
#pragma unroll
        for (int r = 0; r < ROWS; ++r) {
          const float4 hv = *(const float4*)&shb[r][k4 * 4];
          lg[r] = fma4(lg[r], wl, hv);
        }
        wl = wl_n;
      }
#pragma unroll
      for (int r = 0; r < ROWS; ++r) {
        const uint32_t cnt = (uint32_t)((b0 + r) * 512 + j);   // flat idx in [B,V]
        uint32_t o0, o1;
        threefry2x32(k0, k1, 0u, cnt, o0, o1);
        sx[r][j] = __fadd_rn(gumbel_from_bits(o0 ^ o1), __fadd_rn(lg[r], ob));
      }
      __syncthreads();
    }

    // ---- per-row argmax (wave w -> row w), first-index tiebreak ----
    {
      const int r = j >> 6, lane = j & 63;
      float bv = -3.402823466e38f;
      int bi = 0;
#pragma unroll
      for (int i = 0; i < 8; ++i) {
        const int v = i * 64 + lane;
        const float x = sx[r][v];
        if (x > bv) { bv = x; bi = v; }
      }
#pragma unroll
      for (int d = 1; d < 64; d <<= 1) {
        const float ov = __shfl_xor(bv, d, 64);
        const int oi = __shfl_xor(bi, d, 64);
        if (ov > bv || (ov == bv && oi < bi)) { bv = ov; bi = oi; }
      }
      if (lane == 0) {
        bi = bi < 0 ? 0 : (bi > 511 ? 511 : bi);
        stok[r] = bi;
        out[(size_t)(b0 + r) * 100 + t] = bi;
      }
    }
    __syncthreads();
  }
}

// ---------------- host launcher ----------------
extern "C" void kernel_launch(void* const* d_in, const int* in_sizes, int n_in,
                              void* d_out, int out_size, void* d_ws, size_t ws_size,
                              hipStream_t stream) {
  (void)in_sizes; (void)n_in; (void)out_size; (void)d_ws; (void)ws_size;
  const float* P     = (const float*)d_in[0];
  const float* z     = (const float*)d_in[1];
  const float* pe_w1 = (const float*)d_in[2];
  const float* pe_b1 = (const float*)d_in[3];
  const float* pe_w2 = (const float*)d_in[4];
  const float* pe_b2 = (const float*)d_in[5];
  const float* fc_w  = (const float*)d_in[6];
  const float* fc_b  = (const float*)d_in[7];
  const float* wih0  = (const float*)d_in[8];
  const float* whh0  = (const float*)d_in[9];
  const float* bih0  = (const float*)d_in[10];
  const float* bhh0  = (const float*)d_in[11];
  const float* wih1  = (const float*)d_in[12];
  const float* whh1  = (const float*)d_in[13];
  const float* bih1  = (const float*)d_in[14];
  const float* bhh1  = (const float*)d_in[15];
  const float* out_w = (const float*)d_in[16];
  const float* out_b = (const float*)d_in[17];
  int* out = (int*)d_out;

  transpose_any<<<dim3(16, 64), 256, 0, stream>>>(wih0, 2048, 512, 0);
  transpose_any<<<dim3(32, 16), 256, 0, stream>>>(pe_w1, 512, 1024, 5);
  transpose_any<<<dim3(16, 8),  256, 0, stream>>>(pe_w2, 256, 512, 6);
  transpose_any<<<dim3(12, 16), 256, 0, stream>>>(fc_w, 512, 384, 7);

  pack3_kernel<<<768, 256, 0, stream>>>(whh0, 0);
  pack3_kernel<<<768, 256, 0, stream>>>(wih1, 1);
  pack3_kernel<<<768, 256, 0, stream>>>(whh1, 2);
  pack1_kernel<<<256, 256, 0, stream>>>(out_w, 3);

  pe1_kernel<<<4096, 512, 0, stream>>>(P, pe_b1);
  pe2_kernel<<<4096, 256, 0, stream>>>(pe_b2);
  h0_kernel<<<4096, 512, 0, stream>>>(z, fc_b);

  rnn_kernel<<<512, 512, 0, stream>>>(bih0, bhh0, bih1, bhh1, out_b, out);
}

// Round 10
// 45416.721 us; speedup vs baseline: 1.0898x; 1.0898x over previous
//
#include <hip/hip_runtime.h>
#include <cstdint>
#include <cstddef>

#define TINYF 1.17549435e-38f
#define ROWS 8

// ---------------- static device workspace ----------------
// packed streamed weights: [gate][k4][j] float4 = W[goff+j][4k4..4k4+3]
// padded +512 so the software-pipeline prefetch at k4=127 stays in bounds.
__device__ __align__(256) float4 g_pw0[3 * 65536 + 512];   // whh0 (cell0 h-side)
__device__ __align__(256) float4 g_pwx[3 * 65536 + 512];   // wih1 (cell1 x-side)
__device__ __align__(256) float4 g_pwh[3 * 65536 + 512];   // whh1 (cell1 h-side)
__device__ __align__(256) float4 g_plo[65536 + 512];       // out_w (logits)

__device__ __align__(256) float g_wih0T[512 * 2048];   // [tok][gate_row] one-hot gather
__device__ __align__(256) float g_pew1T[1024 * 512];
__device__ __align__(256) float g_pew2T[512 * 256];
__device__ __align__(256) float g_fcwT[384 * 512];
__device__ __align__(256) float g_pe1[4096 * 512];
__device__ __align__(256) float g_pe2[4096 * 256];
__device__ __align__(256) float g_h0[4096 * 512];

__device__ __forceinline__ float* sel_wt(int s) {
  switch (s) {
    case 0: return g_wih0T; case 5: return g_pew1T;
    case 6: return g_pew2T; case 7: return g_fcwT;
    default: return nullptr;
  }
}
__device__ __forceinline__ float4* sel_pack(int s) {
  switch (s) {
    case 0: return g_pw0; case 1: return g_pwx;
    case 2: return g_pwh; case 3: return g_plo;
    default: return nullptr;
  }
}

// ---------------- JAX threefry2x32 (bit-exact) ----------------
__device__ __forceinline__ uint32_t rotl32(uint32_t v, int d) {
  return (v << d) | (v >> (32 - d));
}
__device__ __forceinline__ void threefry2x32(uint32_t k0, uint32_t k1,
                                             uint32_t x0, uint32_t x1,
                                             uint32_t& o0, uint32_t& o1) {
  uint32_t k2 = k0 ^ k1 ^ 0x1BD11BDAu;
#define TF_ROUND(d) { x0 += x1; x1 = rotl32(x1, (d)); x1 ^= x0; }
  x0 += k0; x1 += k1;
  TF_ROUND(13) TF_ROUND(15) TF_ROUND(26) TF_ROUND(6)
  x0 += k1; x1 += k2 + 1u;
  TF_ROUND(17) TF_ROUND(29) TF_ROUND(16) TF_ROUND(24)
  x0 += k2; x1 += k0 + 2u;
  TF_ROUND(13) TF_ROUND(15) TF_ROUND(26) TF_ROUND(6)
  x0 += k0; x1 += k1 + 3u;
  TF_ROUND(17) TF_ROUND(29) TF_ROUND(16) TF_ROUND(24)
  x0 += k1; x1 += k2 + 4u;
  TF_ROUND(13) TF_ROUND(15) TF_ROUND(26) TF_ROUND(6)
  x0 += k2; x1 += k0 + 5u;
#undef TF_ROUND
  o0 = x0; o1 = x1;
}

// partitionable random_bits (32-bit): bits = o0 ^ o1 of TF(key, (0, flat_idx))
__device__ __forceinline__ float gumbel_from_bits(uint32_t bits) {
  float f = __uint_as_float((bits >> 9) | 0x3f800000u) - 1.0f;  // [0,1)
  float u = fmaxf(TINYF, __fadd_rn(f, TINYF));
  return -logf(-logf(u));
}

// XLA-style f32 tanh rational approx.
__device__ __forceinline__ float xla_tanh(float x) {
  float ax = fabsf(x);
  float xc = fminf(fmaxf(x, -7.90531110763549805f), 7.90531110763549805f);
  float x2 = __fmul_rn(xc, xc);
  float p = -2.76076847742355e-16f;
  p = __fadd_rn(__fmul_rn(p, x2), 2.00018790482477e-13f);
  p = __fadd_rn(__fmul_rn(p, x2), -8.60467152213735e-11f);
  p = __fadd_rn(__fmul_rn(p, x2), 5.12229709037114e-08f);
  p = __fadd_rn(__fmul_rn(p, x2), 1.48572235717979e-05f);
  p = __fadd_rn(__fmul_rn(p, x2), 6.37261928875436e-04f);
  p = __fadd_rn(__fmul_rn(p, x2), 4.89352455891786e-03f);
  p = __fmul_rn(p, xc);
  float q = 1.19825839466702e-06f;
  q = __fadd_rn(__fmul_rn(q, x2), 1.18534705686654e-04f);
  q = __fadd_rn(__fmul_rn(q, x2), 2.26843463243900e-03f);
  q = __fadd_rn(__fmul_rn(q, x2), 4.89352518554385e-03f);
  float r = __fdiv_rn(p, q);
  return (ax < 0.0004f) ? x : r;
}
__device__ __forceinline__ float xla_sigmoid(float x) {
  return __fdiv_rn(1.0f, __fadd_rn(1.0f, expf(-x)));
}

// fma of a float4 pair into a scalar accumulator, ascending component order
__device__ __forceinline__ float fma4(float acc, const float4& a, const float4& b) {
  acc = __builtin_fmaf(a.x, b.x, acc);
  acc = __builtin_fmaf(a.y, b.y, acc);
  acc = __builtin_fmaf(a.z, b.z, acc);
  acc = __builtin_fmaf(a.w, b.w, acc);
  return acc;
}

// ---------------- setup: transpose + pack ----------------
__global__ __launch_bounds__(256) void transpose_any(const float* __restrict__ in,
                                                     int R, int C, int wt_sel) {
  float* out = sel_wt(wt_sel);
  __shared__ float tile[32][33];
  const int c0 = blockIdx.x * 32, r0 = blockIdx.y * 32;
  const int tx = threadIdx.x & 31, ty = threadIdx.x >> 5;
#pragma unroll
  for (int i = 0; i < 32; i += 8)
    tile[ty + i][tx] = in[(size_t)(r0 + ty + i) * C + c0 + tx];
  __syncthreads();
#pragma unroll
  for (int i = 0; i < 32; i += 8)
    out[(size_t)(c0 + ty + i) * R + r0 + tx] = tile[tx][ty + i];
}

__global__ __launch_bounds__(256) void pack3_kernel(const float* __restrict__ src,
                                                    int dst_sel) {
  const int id = blockIdx.x * 256 + threadIdx.x;      // 196608 total
  const int g = id >> 16;
  const int rem = id & 65535;
  const int k4 = rem >> 9, j = rem & 511;
  const int goff[3] = {0, 1024, 1536};
  const float4 v = *(const float4*)&src[(size_t)(goff[g] + j) * 512 + k4 * 4];
  sel_pack(dst_sel)[id] = v;
}

__global__ __launch_bounds__(256) void pack1_kernel(const float* __restrict__ src,
                                                    int dst_sel) {
  const int id = blockIdx.x * 256 + threadIdx.x;      // 65536 total
  const int k4 = id >> 9, j = id & 511;
  const float4 v = *(const float4*)&src[(size_t)j * 512 + k4 * 4];
  sel_pack(dst_sel)[id] = v;
}

// ---------------- prefix: pe1, pe2, h0 ----------------
__global__ __launch_bounds__(512) void pe1_kernel(const float* __restrict__ P,
                                                  const float* __restrict__ b1) {
  __shared__ float a[1024];
  const int b = blockIdx.x, j = threadIdx.x;
  a[j] = P[(size_t)b * 1024 + j];
  a[j + 512] = P[(size_t)b * 1024 + j + 512];
  __syncthreads();
  float acc = 0.0f;
  for (int k = 0; k < 1024; ++k) acc += g_pew1T[(size_t)k * 512 + j] * a[k];
  g_pe1[(size_t)b * 512 + j] = fmaxf(__fadd_rn(acc, b1[j]), 0.0f);
}

__global__ __launch_bounds__(256) void pe2_kernel(const float* __restrict__ b2) {
  __shared__ float a[512];
  const int b = blockIdx.x, j = threadIdx.x;
  a[j] = g_pe1[(size_t)b * 512 + j];
  a[j + 256] = g_pe1[(size_t)b * 512 + j + 256];
  __syncthreads();
  float acc = 0.0f;
  for (int k = 0; k < 512; ++k) acc += g_pew2T[(size_t)k * 256 + j] * a[k];
  g_pe2[(size_t)b * 256 + j] = fmaxf(__fadd_rn(acc, b2[j]), 0.0f);
}

__global__ __launch_bounds__(512) void h0_kernel(const float* __restrict__ z,
                                                 const float* __restrict__ fcb) {
  __shared__ float a[384];
  const int b = blockIdx.x, j = threadIdx.x;
  if (j < 128) a[j] = z[(size_t)b * 128 + j];
  if (j < 256) a[128 + j] = g_pe2[(size_t)b * 256 + j];
  __syncthreads();
  float acc = 0.0f;
  for (int k = 0; k < 384; ++k) acc += g_fcwT[(size_t)k * 512 + j] * a[k];
  g_h0[(size_t)b * 512 + j] = __fadd_rn(acc, fcb[j]);
}

// ---------------- fused 100-step recurrence ----------------
// 512 blocks x 8 rows; 256 threads (4 waves); each thread owns output columns
// j and j+256 -> each broadcast LDS read of h feeds 2x the FMAs (LDS-pipe
// relief). cell1 split into x-pass / h-pass to bound accumulator VGPRs; all
// per-accumulator arithmetic orders identical to the verified round-7 kernel.
__global__ __launch_bounds__(256) void rnn_kernel(
    const float* __restrict__ bih0, const float* __restrict__ bhh0,
    const float* __restrict__ bih1, const float* __restrict__ bhh1,
    const float* __restrict__ outb, int* __restrict__ out) {
  __shared__ float sha[ROWS][512];
  __shared__ float shb[ROWS][512];
  __shared__ float sx[ROWS][512];
  __shared__ int stok[ROWS];

  const int j = threadIdx.x;             // 0..255; owns cols j and j+256
  const int b0 = blockIdx.x * ROWS;

  float bc0i[2], bc0g[2], bc0o[2], bc1i[2], bc1g[2], bc1o[2], ob[2];
#pragma unroll
  for (int c = 0; c < 2; ++c) {
    const int col = j + c * 256;
    bc0i[c] = __fadd_rn(bih0[col],        bhh0[col]);
    bc0g[c] = __fadd_rn(bih0[1024 + col], bhh0[1024 + col]);
    bc0o[c] = __fadd_rn(bih0[1536 + col], bhh0[1536 + col]);
    bc1i[c] = __fadd_rn(bih1[col],        bhh1[col]);
    bc1g[c] = __fadd_rn(bih1[1024 + col], bhh1[1024 + col]);
    bc1o[c] = __fadd_rn(bih1[1536 + col], bhh1[1536 + col]);
    ob[c]   = outb[col];
  }

#pragma unroll
  for (int r = 0; r < ROWS; ++r)
#pragma unroll
    for (int c = 0; c < 2; ++c) {
      const int col = j + c * 256;
      const float h0 = g_h0[(size_t)(b0 + r) * 512 + col];
      sha[r][col] = h0;
      shb[r][col] = h0;
    }
  if (j < ROWS) stok[j] = 511;
  __syncthreads();

  for (int t = 0; t < 100; ++t) {
    uint32_t k0, k1;
    threefry2x32(0u, 1u, 0u, (uint32_t)t, k0, k1);   // keys[t] (partitionable)

    // ---- cell0 h-term: ha @ whh0^T (gates i,g,o; f dead) ----
    {
      float ai[ROWS][2], ag[ROWS][2], ao[ROWS][2];
#pragma unroll
      for (int r = 0; r < ROWS; ++r)
#pragma unroll
        for (int c = 0; c < 2; ++c) { ai[r][c] = 0.0f; ag[r][c] = 0.0f; ao[r][c] = 0.0f; }
      float4 wi[2], wg[2], wo[2];
#pragma unroll
      for (int c = 0; c < 2; ++c) {
        wi[c] = g_pw0[j + c * 256];
        wg[c] = g_pw0[65536 + j + c * 256];
        wo[c] = g_pw0[131072 + j + c * 256];
      }
#pragma unroll 1
      for (int k4 = 0; k4 < 128; ++k4) {
        const int nx = (k4 + 1) * 512;
        float4 wi_n[2], wg_n[2], wo_n[2];
#pragma unroll
        for (int c = 0; c < 2; ++c) {
          wi_n[c] = g_pw0[nx + j + c * 256];
          wg_n[c] = g_pw0[65536 + nx + j + c * 256];
          wo_n[c] = g_pw0[131072 + nx + j + c * 256];
        }
#pragma unroll
        for (int r = 0; r < ROWS; ++r) {
          const float4 hv = *(const float4*)&sha[r][k4 * 4];
#pragma unroll
          for (int c = 0; c < 2; ++c) {
            ai[r][c] = fma4(ai[r][c], wi[c], hv);
            ag[r][c] = fma4(ag[r][c], wg[c], hv);
            ao[r][c] = fma4(ao[r][c], wo[c], hv);
          }
        }
#pragma unroll
        for (int c = 0; c < 2; ++c) { wi[c] = wi_n[c]; wg[c] = wg_n[c]; wo[c] = wo_n[c]; }
      }
      __syncthreads();                    // all reads of sha complete
#pragma unroll
      for (int r = 0; r < ROWS; ++r) {
        const float* xr = g_wih0T + (size_t)stok[r] * 2048;  // exact one-hot x-term
#pragma unroll
        for (int c = 0; c < 2; ++c) {
          const int col = j + c * 256;
          const float iv = __fadd_rn(__fadd_rn(xr[col],        ai[r][c]), bc0i[c]);
          const float gv = __fadd_rn(__fadd_rn(xr[1024 + col], ag[r][c]), bc0g[c]);
          const float ov = __fadd_rn(__fadd_rn(xr[1536 + col], ao[r][c]), bc0o[c]);
          const float cc = __fmul_rn(xla_sigmoid(iv), xla_tanh(gv));
          sha[r][col] = __fmul_rn(xla_sigmoid(ov), xla_tanh(cc));
        }
      }
      __syncthreads();                    // sha now holds ha'
    }

    // ---- cell1: ha' @ wih1^T + hb @ whh1^T (x-pass then h-pass) ----
    {
      float xi[ROWS][2], xg[ROWS][2], xo[ROWS][2];
#pragma unroll
      for (int r = 0; r < ROWS; ++r)
#pragma unroll
        for (int c = 0; c < 2; ++c) { xi[r][c] = 0.0f; xg[r][c] = 0.0f; xo[r][c] = 0.0f; }
      {
        float4 wi[2], wg[2], wo[2];
#pragma unroll
        for (int c = 0; c < 2; ++c) {
          wi[c] = g_pwx[j + c * 256];
          wg[c] = g_pwx[65536 + j + c * 256];
          wo[c] = g_pwx[131072 + j + c * 256];
        }
#pragma unroll 1
        for (int k4 = 0; k4 < 128; ++k4) {
          const int nx = (k4 + 1) * 512;
          float4 wi_n[2], wg_n[2], wo_n[2];
#pragma unroll
          for (int c = 0; c < 2; ++c) {
            wi_n[c] = g_pwx[nx + j + c * 256];
            wg_n[c] = g_pwx[65536 + nx + j + c * 256];
            wo_n[c] = g_pwx[131072 + nx + j + c * 256];
          }
#pragma unroll
          for (int r = 0; r < ROWS; ++r) {
            const float4 xv = *(const float4*)&sha[r][k4 * 4];
#pragma unroll
            for (int c = 0; c < 2; ++c) {
              xi[r][c] = fma4(xi[r][c], wi[c], xv);
              xg[r][c] = fma4(xg[r][c], wg[c], xv);
              xo[r][c] = fma4(xo[r][c], wo[c], xv);
            }
          }
#pragma unroll
          for (int c = 0; c < 2; ++c) { wi[c] = wi_n[c]; wg[c] = wg_n[c]; wo[c] = wo_n[c]; }
        }
      }
      float hi[ROWS][2], hg[ROWS][2], ho[ROWS][2];
#pragma unroll
      for (int r = 0; r < ROWS; ++r)
#pragma unroll
        for (int c = 0; c < 2; ++c) { hi[r][c] = 0.0f; hg[r][c] = 0.0f; ho[r][c] = 0.0f; }
      {
        float4 wi[2], wg[2], wo[2];
#pragma unroll
        for (int c = 0; c < 2; ++c) {
          wi[c] = g_pwh[j + c * 256];
          wg[c] = g_pwh[65536 + j + c * 256];
          wo[c] = g_pwh[131072 + j + c * 256];
        }
#pragma unroll 1
        for (int k4 = 0; k4 < 128; ++k4) {
          const int nx = (k4 + 1) * 512;
          float4 wi_n[2], wg_n[2], wo_n[2];
#pragma unroll
          for (int c = 0; c < 2; ++c) {
            wi_n[c] = g_pwh[nx + j + c * 256];
            wg_n[c] = g_pwh[65536 + nx + j + c * 256];
            wo_n[c] = g_pwh[131072 + nx + j + c * 256];
          }
#pragma unroll
          for (int r = 0; r < ROWS; ++r) {
            const float4 hv = *(const float4*)&shb[r][k4 * 4];
#pragma unroll
            for (int c = 0; c < 2; ++c) {
              hi[r][c] = fma4(hi[r][c], wi[c], hv);
              hg[r][c] = fma4(hg[r][c], wg[c], hv);
              ho[r][c] = fma4(ho[r][c], wo[c], hv);
            }
          }
#pragma unroll
          for (int c = 0; c < 2; ++c) { wi[c] = wi_n[c]; wg[c] = wg_n[c]; wo[c] = wo_n[c]; }
        }
      }
      __syncthreads();                    // all reads of sha/shb complete
#pragma unroll
      for (int r = 0; r < ROWS; ++r)
#pragma unroll
        for (int c = 0; c < 2; ++c) {
          const int col = j + c * 256;
          const float iv = __fadd_rn(__fadd_rn(xi[r][c], hi[r][c]), bc1i[c]);
          const float gv = __fadd_rn(__fadd_rn(xg[r][c], hg[r][c]), bc1g[c]);
          const float ov = __fadd_rn(__fadd_rn(xo[r][c], ho[r][c]), bc1o[c]);
          const float cc = __fmul_rn(xla_sigmoid(iv), xla_tanh(gv));
          shb[r][col] = __fmul_rn(xla_sigmoid(ov), xla_tanh(cc));
        }
      __syncthreads();                    // shb now holds hb'
    }

    // ---- logits + gumbel ----
    {
      float lg[ROWS][2];
#pragma unroll
      for (int r = 0; r < ROWS; ++r) { lg[r][0] = 0.0f; lg[r][1] = 0.0f; }
      float4 wl[2];
      wl[0] = g_plo[j]; wl[1] = g_plo[j + 256];
#pragma unroll 1
      for (int k4 = 0; k4 < 128; ++k4) {
        const int nx = (k4 + 1) * 512;
        float4 wl_n[2];
        wl_n[0] = g_plo[nx + j]; wl_n[1] = g_plo[nx + j + 256];
#pragma unroll
        for (int r = 0; r < ROWS; ++r) {
          const float4 hv = *(const float4*)&shb[r][k4 * 4];
          lg[r][0] = fma4(lg[r][0], wl[0], hv);
          lg[r][1] = fma4(lg[r][1], wl[1], hv);
        }
        wl[0] = wl_n[0]; wl[1] = wl_n[1];
      }
#pragma unroll
      for (int r = 0; r < ROWS; ++r)
#pragma unroll
        for (int c = 0; c < 2; ++c) {
          const int col = j + c * 256;
          const uint32_t cnt = (uint32_t)((b0 + r) * 512 + col);
          uint32_t o0, o1;
          threefry2x32(k0, k1, 0u, cnt, o0, o1);
          sx[r][col] = __fadd_rn(gumbel_from_bits(o0 ^ o1), __fadd_rn(lg[r][c], ob[c]));
        }
      __syncthreads();
    }

    // ---- per-row argmax: 4 waves, 2 rows each, first-index tiebreak ----
    {
      const int w = j >> 6, lane = j & 63;
#pragma unroll
      for (int rr = 0; rr < 2; ++rr) {
        const int r = w * 2 + rr;
        float bv = -3.402823466e38f;
        int bi = 0;
#pragma unroll
        for (int i = 0; i < 8; ++i) {
          const int v = i * 64 + lane;
          const float x = sx[r][v];
          if (x > bv) { bv = x; bi = v; }
        }
#pragma unroll
        for (int d = 1; d < 64; d <<= 1) {
          const float ov = __shfl_xor(bv, d, 64);
          const int oi = __shfl_xor(bi, d, 64);
          if (ov > bv || (ov == bv && oi < bi)) { bv = ov; bi = oi; }
        }
        if (lane == 0) {
          bi = bi < 0 ? 0 : (bi > 511 ? 511 : bi);
          stok[r] = bi;
          out[(size_t)(b0 + r) * 100 + t] = bi;
        }
      }
    }
    __syncthreads();
  }
}

// ---------------- host launcher ----------------
extern "C" void kernel_launch(void* const* d_in, const int* in_sizes, int n_in,
                              void* d_out, int out_size, void* d_ws, size_t ws_size,
                              hipStream_t stream) {
  (void)in_sizes; (void)n_in; (void)out_size; (void)d_ws; (void)ws_size;
  const float* P     = (const float*)d_in[0];
  const float* z     = (const float*)d_in[1];
  const float* pe_w1 = (const float*)d_in[2];
  const float* pe_b1 = (const float*)d_in[3];
  const float* pe_w2 = (const float*)d_in[4];
  const float* pe_b2 = (const float*)d_in[5];
  const float* fc_w  = (const float*)d_in[6];
  const float* fc_b  = (const float*)d_in[7];
  const float* wih0  = (const float*)d_in[8];
  const float* whh0  = (const float*)d_in[9];
  const float* bih0  = (const float*)d_in[10];
  const float* bhh0  = (const float*)d_in[11];
  const float* wih1  = (const float*)d_in[12];
  const float* whh1  = (const float*)d_in[13];
  const float* bih1  = (const float*)d_in[14];
  const float* bhh1  = (const float*)d_in[15];
  const float* out_w = (const float*)d_in[16];
  const float* out_b = (const float*)d_in[17];
  int* out = (int*)d_out;

  transpose_any<<<dim3(16, 64), 256, 0, stream>>>(wih0, 2048, 512, 0);
  transpose_any<<<dim3(32, 16), 256, 0, stream>>>(pe_w1, 512, 1024, 5);
  transpose_any<<<dim3(16, 8),  256, 0, stream>>>(pe_w2, 256, 512, 6);
  transpose_any<<<dim3(12, 16), 256, 0, stream>>>(fc_w, 512, 384, 7);

  pack3_kernel<<<768, 256, 0, stream>>>(whh0, 0);
  pack3_kernel<<<768, 256, 0, stream>>>(wih1, 1);
  pack3_kernel<<<768, 256, 0, stream>>>(whh1, 2);
  pack1_kernel<<<256, 256, 0, stream>>>(out_w, 3);

  pe1_kernel<<<4096, 512, 0, stream>>>(P, pe_b1);
  pe2_kernel<<<4096, 256, 0, stream>>>(pe_b2);
  h0_kernel<<<4096, 512, 0, stream>>>(z, fc_b);

  rnn_kernel<<<512, 256, 0, stream>>>(bih0, bhh0, bih1, bhh1, out_b, out);
}

// Round 11
// 36160.806 us; speedup vs baseline: 1.3687x; 1.2560x over previous
//
#include <hip/hip_runtime.h>
#include <cstdint>
#include <cstddef>

#define TINYF 1.17549435e-38f
#define ROWS 8
#define LDSW 516   // padded row width: allows blind k4+1 prefetch at k4=127

// ---------------- static device workspace ----------------
// packed streamed weights: [gate][k4][j] float4 = W[goff+j][4k4..4k4+3]
// padded +512 so the software-pipeline prefetch at k4=127 stays in bounds.
__device__ __align__(256) float4 g_pw0[3 * 65536 + 512];   // whh0 (cell0 h-side)
__device__ __align__(256) float4 g_pwx[3 * 65536 + 512];   // wih1 (cell1 x-side)
__device__ __align__(256) float4 g_pwh[3 * 65536 + 512];   // whh1 (cell1 h-side)
__device__ __align__(256) float4 g_plo[65536 + 512];       // out_w (logits)

__device__ __align__(256) float g_wih0T[512 * 2048];   // [tok][gate_row] one-hot gather
__device__ __align__(256) float g_pew1T[1024 * 512];
__device__ __align__(256) float g_pew2T[512 * 256];
__device__ __align__(256) float g_fcwT[384 * 512];
__device__ __align__(256) float g_pe1[4096 * 512];
__device__ __align__(256) float g_pe2[4096 * 256];
__device__ __align__(256) float g_h0[4096 * 512];

__device__ __forceinline__ float* sel_wt(int s) {
  switch (s) {
    case 0: return g_wih0T; case 5: return g_pew1T;
    case 6: return g_pew2T; case 7: return g_fcwT;
    default: return nullptr;
  }
}
__device__ __forceinline__ float4* sel_pack(int s) {
  switch (s) {
    case 0: return g_pw0; case 1: return g_pwx;
    case 2: return g_pwh; case 3: return g_plo;
    default: return nullptr;
  }
}

// ---------------- JAX threefry2x32 (bit-exact) ----------------
__device__ __forceinline__ uint32_t rotl32(uint32_t v, int d) {
  return (v << d) | (v >> (32 - d));
}
__device__ __forceinline__ void threefry2x32(uint32_t k0, uint32_t k1,
                                             uint32_t x0, uint32_t x1,
                                             uint32_t& o0, uint32_t& o1) {
  uint32_t k2 = k0 ^ k1 ^ 0x1BD11BDAu;
#define TF_ROUND(d) { x0 += x1; x1 = rotl32(x1, (d)); x1 ^= x0; }
  x0 += k0; x1 += k1;
  TF_ROUND(13) TF_ROUND(15) TF_ROUND(26) TF_ROUND(6)
  x0 += k1; x1 += k2 + 1u;
  TF_ROUND(17) TF_ROUND(29) TF_ROUND(16) TF_ROUND(24)
  x0 += k2; x1 += k0 + 2u;
  TF_ROUND(13) TF_ROUND(15) TF_ROUND(26) TF_ROUND(6)
  x0 += k0; x1 += k1 + 3u;
  TF_ROUND(17) TF_ROUND(29) TF_ROUND(16) TF_ROUND(24)
  x0 += k1; x1 += k2 + 4u;
  TF_ROUND(13) TF_ROUND(15) TF_ROUND(26) TF_ROUND(6)
  x0 += k2; x1 += k0 + 5u;
#undef TF_ROUND
  o0 = x0; o1 = x1;
}

// partitionable random_bits (32-bit): bits = o0 ^ o1 of TF(key, (0, flat_idx))
__device__ __forceinline__ float gumbel_from_bits(uint32_t bits) {
  float f = __uint_as_float((bits >> 9) | 0x3f800000u) - 1.0f;  // [0,1)
  float u = fmaxf(TINYF, __fadd_rn(f, TINYF));
  return -logf(-logf(u));
}

// XLA-style f32 tanh rational approx.
__device__ __forceinline__ float xla_tanh(float x) {
  float ax = fabsf(x);
  float xc = fminf(fmaxf(x, -7.90531110763549805f), 7.90531110763549805f);
  float x2 = __fmul_rn(xc, xc);
  float p = -2.76076847742355e-16f;
  p = __fadd_rn(__fmul_rn(p, x2), 2.00018790482477e-13f);
  p = __fadd_rn(__fmul_rn(p, x2), -8.60467152213735e-11f);
  p = __fadd_rn(__fmul_rn(p, x2), 5.12229709037114e-08f);
  p = __fadd_rn(__fmul_rn(p, x2), 1.48572235717979e-05f);
  p = __fadd_rn(__fmul_rn(p, x2), 6.37261928875436e-04f);
  p = __fadd_rn(__fmul_rn(p, x2), 4.89352455891786e-03f);
  p = __fmul_rn(p, xc);
  float q = 1.19825839466702e-06f;
  q = __fadd_rn(__fmul_rn(q, x2), 1.18534705686654e-04f);
  q = __fadd_rn(__fmul_rn(q, x2), 2.26843463243900e-03f);
  q = __fadd_rn(__fmul_rn(q, x2), 4.89352518554385e-03f);
  float r = __fdiv_rn(p, q);
  return (ax < 0.0004f) ? x : r;
}
__device__ __forceinline__ float xla_sigmoid(float x) {
  return __fdiv_rn(1.0f, __fadd_rn(1.0f, expf(-x)));
}

// fma of a float4 pair into a scalar accumulator, ascending component order
__device__ __forceinline__ float fma4(float acc, const float4& a, const float4& b) {
  acc = __builtin_fmaf(a.x, b.x, acc);
  acc = __builtin_fmaf(a.y, b.y, acc);
  acc = __builtin_fmaf(a.z, b.z, acc);
  acc = __builtin_fmaf(a.w, b.w, acc);
  return acc;
}

// ---------------- setup: transpose + pack ----------------
__global__ __launch_bounds__(256) void transpose_any(const float* __restrict__ in,
                                                     int R, int C, int wt_sel) {
  float* out = sel_wt(wt_sel);
  __shared__ float tile[32][33];
  const int c0 = blockIdx.x * 32, r0 = blockIdx.y * 32;
  const int tx = threadIdx.x & 31, ty = threadIdx.x >> 5;
#pragma unroll
  for (int i = 0; i < 32; i += 8)
    tile[ty + i][tx] = in[(size_t)(r0 + ty + i) * C + c0 + tx];
  __syncthreads();
#pragma unroll
  for (int i = 0; i < 32; i += 8)
    out[(size_t)(c0 + ty + i) * R + r0 + tx] = tile[tx][ty + i];
}

__global__ __launch_bounds__(256) void pack3_kernel(const float* __restrict__ src,
                                                    int dst_sel) {
  const int id = blockIdx.x * 256 + threadIdx.x;      // 196608 total
  const int g = id >> 16;
  const int rem = id & 65535;
  const int k4 = rem >> 9, j = rem & 511;
  const int goff[3] = {0, 1024, 1536};
  const float4 v = *(const float4*)&src[(size_t)(goff[g] + j) * 512 + k4 * 4];
  sel_pack(dst_sel)[id] = v;
}

__global__ __launch_bounds__(256) void pack1_kernel(const float* __restrict__ src,
                                                    int dst_sel) {
  const int id = blockIdx.x * 256 + threadIdx.x;      // 65536 total
  const int k4 = id >> 9, j = id & 511;
  const float4 v = *(const float4*)&src[(size_t)j * 512 + k4 * 4];
  sel_pack(dst_sel)[id] = v;
}

// ---------------- prefix: pe1, pe2, h0 ----------------
__global__ __launch_bounds__(512) void pe1_kernel(const float* __restrict__ P,
                                                  const float* __restrict__ b1) {
  __shared__ float a[1024];
  const int b = blockIdx.x, j = threadIdx.x;
  a[j] = P[(size_t)b * 1024 + j];
  a[j + 512] = P[(size_t)b * 1024 + j + 512];
  __syncthreads();
  float acc = 0.0f;
  for (int k = 0; k < 1024; ++k) acc += g_pew1T[(size_t)k * 512 + j] * a[k];
  g_pe1[(size_t)b * 512 + j] = fmaxf(__fadd_rn(acc, b1[j]), 0.0f);
}

__global__ __launch_bounds__(256) void pe2_kernel(const float* __restrict__ b2) {
  __shared__ float a[512];
  const int b = blockIdx.x, j = threadIdx.x;
  a[j] = g_pe1[(size_t)b * 512 + j];
  a[j + 256] = g_pe1[(size_t)b * 512 + j + 256];
  __syncthreads();
  float acc = 0.0f;
  for (int k = 0; k < 512; ++k) acc += g_pew2T[(size_t)k * 256 + j] * a[k];
  g_pe2[(size_t)b * 256 + j] = fmaxf(__fadd_rn(acc, b2[j]), 0.0f);
}

__global__ __launch_bounds__(512) void h0_kernel(const float* __restrict__ z,
                                                 const float* __restrict__ fcb) {
  __shared__ float a[384];
  const int b = blockIdx.x, j = threadIdx.x;
  if (j < 128) a[j] = z[(size_t)b * 128 + j];
  if (j < 256) a[128 + j] = g_pe2[(size_t)b * 256 + j];
  __syncthreads();
  float acc = 0.0f;
  for (int k = 0; k < 384; ++k) acc += g_fcwT[(size_t)k * 512 + j] * a[k];
  g_h0[(size_t)b * 512 + j] = __fadd_rn(acc, fcb[j]);
}

// ---------------- fused 100-step recurrence ----------------
// 512 blocks x 8 rows; 256 threads (4 waves); each thread owns cols j, j+256.
// Both the weight stream (global) AND the h broadcast reads (LDS) are now
// software-pipelined one k4 ahead, so ds_read latency hides under FMAs.
// Per-accumulator arithmetic identical to the verified round-7/10 kernels.
__global__ __launch_bounds__(256) void rnn_kernel(
    const float* __restrict__ bih0, const float* __restrict__ bhh0,
    const float* __restrict__ bih1, const float* __restrict__ bhh1,
    const float* __restrict__ outb, int* __restrict__ out) {
  __shared__ float sha[ROWS][LDSW];      // padded; [r][512..515] is junk pad
  __shared__ float shb[ROWS][LDSW];
  __shared__ float sx[ROWS][512];
  __shared__ int stok[ROWS];

  const int j = threadIdx.x;             // 0..255; owns cols j and j+256
  const int b0 = blockIdx.x * ROWS;

  float bc0i[2], bc0g[2], bc0o[2], bc1i[2], bc1g[2], bc1o[2], ob[2];
#pragma unroll
  for (int c = 0; c < 2; ++c) {
    const int col = j + c * 256;
    bc0i[c] = __fadd_rn(bih0[col],        bhh0[col]);
    bc0g[c] = __fadd_rn(bih0[1024 + col], bhh0[1024 + col]);
    bc0o[c] = __fadd_rn(bih0[1536 + col], bhh0[1536 + col]);
    bc1i[c] = __fadd_rn(bih1[col],        bhh1[col]);
    bc1g[c] = __fadd_rn(bih1[1024 + col], bhh1[1024 + col]);
    bc1o[c] = __fadd_rn(bih1[1536 + col], bhh1[1536 + col]);
    ob[c]   = outb[col];
  }

#pragma unroll
  for (int r = 0; r < ROWS; ++r)
#pragma unroll
    for (int c = 0; c < 2; ++c) {
      const int col = j + c * 256;
      const float h0 = g_h0[(size_t)(b0 + r) * 512 + col];
      sha[r][col] = h0;
      shb[r][col] = h0;
    }
  if (j < ROWS) stok[j] = 511;
  __syncthreads();

  for (int t = 0; t < 100; ++t) {
    uint32_t k0, k1;
    threefry2x32(0u, 1u, 0u, (uint32_t)t, k0, k1);   // keys[t] (partitionable)

    // ---- cell0 h-term: ha @ whh0^T (gates i,g,o; f dead) ----
    {
      float ai[ROWS][2], ag[ROWS][2], ao[ROWS][2];
#pragma unroll
      for (int r = 0; r < ROWS; ++r)
#pragma unroll
        for (int c = 0; c < 2; ++c) { ai[r][c] = 0.0f; ag[r][c] = 0.0f; ao[r][c] = 0.0f; }
      float4 wi[2], wg[2], wo[2], hv[ROWS];
#pragma unroll
      for (int c = 0; c < 2; ++c) {
        wi[c] = g_pw0[j + c * 256];
        wg[c] = g_pw0[65536 + j + c * 256];
        wo[c] = g_pw0[131072 + j + c * 256];
      }
#pragma unroll
      for (int r = 0; r < ROWS; ++r) hv[r] = *(const float4*)&sha[r][0];
#pragma unroll 1
      for (int k4 = 0; k4 < 128; ++k4) {
        const int nx = (k4 + 1) * 512;
        float4 wi_n[2], wg_n[2], wo_n[2], hv_n[ROWS];
#pragma unroll
        for (int r = 0; r < ROWS; ++r)
          hv_n[r] = *(const float4*)&sha[r][(k4 + 1) * 4];   // pad-safe at 127
#pragma unroll
        for (int c = 0; c < 2; ++c) {
          wi_n[c] = g_pw0[nx + j + c * 256];
          wg_n[c] = g_pw0[65536 + nx + j + c * 256];
          wo_n[c] = g_pw0[131072 + nx + j + c * 256];
        }
#pragma unroll
        for (int r = 0; r < ROWS; ++r)
#pragma unroll
          for (int c = 0; c < 2; ++c) {
            ai[r][c] = fma4(ai[r][c], wi[c], hv[r]);
            ag[r][c] = fma4(ag[r][c], wg[c], hv[r]);
            ao[r][c] = fma4(ao[r][c], wo[c], hv[r]);
          }
#pragma unroll
        for (int r = 0; r < ROWS; ++r) hv[r] = hv_n[r];
#pragma unroll
        for (int c = 0; c < 2; ++c) { wi[c] = wi_n[c]; wg[c] = wg_n[c]; wo[c] = wo_n[c]; }
      }
      __syncthreads();                    // all reads of sha complete
#pragma unroll
      for (int r = 0; r < ROWS; ++r) {
        const float* xr = g_wih0T + (size_t)stok[r] * 2048;  // exact one-hot x-term
#pragma unroll
        for (int c = 0; c < 2; ++c) {
          const int col = j + c * 256;
          const float iv = __fadd_rn(__fadd_rn(xr[col],        ai[r][c]), bc0i[c]);
          const float gv = __fadd_rn(__fadd_rn(xr[1024 + col], ag[r][c]), bc0g[c]);
          const float ov = __fadd_rn(__fadd_rn(xr[1536 + col], ao[r][c]), bc0o[c]);
          const float cc = __fmul_rn(xla_sigmoid(iv), xla_tanh(gv));
          sha[r][col] = __fmul_rn(xla_sigmoid(ov), xla_tanh(cc));
        }
      }
      __syncthreads();                    // sha now holds ha'
    }

    // ---- cell1: ha' @ wih1^T + hb @ whh1^T (x-pass then h-pass) ----
    {
      float xi[ROWS][2], xg[ROWS][2], xo[ROWS][2];
#pragma unroll
      for (int r = 0; r < ROWS; ++r)
#pragma unroll
        for (int c = 0; c < 2; ++c) { xi[r][c] = 0.0f; xg[r][c] = 0.0f; xo[r][c] = 0.0f; }
      {
        float4 wi[2], wg[2], wo[2], hv[ROWS];
#pragma unroll
        for (int c = 0; c < 2; ++c) {
          wi[c] = g_pwx[j + c * 256];
          wg[c] = g_pwx[65536 + j + c * 256];
          wo[c] = g_pwx[131072 + j + c * 256];
        }
#pragma unroll
        for (int r = 0; r < ROWS; ++r) hv[r] = *(const float4*)&sha[r][0];
#pragma unroll 1
        for (int k4 = 0; k4 < 128; ++k4) {
          const int nx = (k4 + 1) * 512;
          float4 wi_n[2], wg_n[2], wo_n[2], hv_n[ROWS];
#pragma unroll
          for (int r = 0; r < ROWS; ++r)
            hv_n[r] = *(const float4*)&sha[r][(k4 + 1) * 4];
#pragma unroll
          for (int c = 0; c < 2; ++c) {
            wi_n[c] = g_pwx[nx + j + c * 256];
            wg_n[c] = g_pwx[65536 + nx + j + c * 256];
            wo_n[c] = g_pwx[131072 + nx + j + c * 256];
          }
#pragma unroll
          for (int r = 0; r < ROWS; ++r)
#pragma unroll
            for (int c = 0; c < 2; ++c) {
              xi[r][c] = fma4(xi[r][c], wi[c], hv[r]);
              xg[r][c] = fma4(xg[r][c], wg[c], hv[r]);
              xo[r][c] = fma4(xo[r][c], wo[c], hv[r]);
            }
#pragma unroll
          for (int r = 0; r < ROWS; ++r) hv[r] = hv_n[r];
#pragma unroll
          for (int c = 0; c < 2; ++c) { wi[c] = wi_n[c]; wg[c] = wg_n[c]; wo[c] = wo_n[c]; }
        }
      }
      float hi[ROWS][2], hg[ROWS][2], ho[ROWS][2];
#pragma unroll
      for (int r = 0; r < ROWS; ++r)
#pragma unroll
        for (int c = 0; c < 2; ++c) { hi[r][c] = 0.0f; hg[r][c] = 0.0f; ho[r][c] = 0.0f; }
      {
        float4 wi[2], wg[2], wo[2], hv[ROWS];
#pragma unroll
        for (int c = 0; c < 2; ++c) {
          wi[c] = g_pwh[j + c * 256];
          wg[c] = g_pwh[65536 + j + c * 256];
          wo[c] = g_pwh[131072 + j + c * 256];
        }
#pragma unroll
        for (int r = 0; r < ROWS; ++r) hv[r] = *(const float4*)&shb[r][0];
#pragma unroll 1
        for (int k4 = 0; k4 < 128; ++k4) {
          const int nx = (k4 + 1) * 512;
          float4 wi_n[2], wg_n[2], wo_n[2], hv_n[ROWS];
#pragma unroll
          for (int r = 0; r < ROWS; ++r)
            hv_n[r] = *(const float4*)&shb[r][(k4 + 1) * 4];
#pragma unroll
          for (int c = 0; c < 2; ++c) {
            wi_n[c] = g_pwh[nx + j + c * 256];
            wg_n[c] = g_pwh[65536 + nx + j + c * 256];
            wo_n[c] = g_pwh[131072 + nx + j + c * 256];
          }
#pragma unroll
          for (int r = 0; r < ROWS; ++r)
#pragma unroll
            for (int c = 0; c < 2; ++c) {
              hi[r][c] = fma4(hi[r][c], wi[c], hv[r]);
              hg[r][c] = fma4(hg[r][c], wg[c], hv[r]);
              ho[r][c] = fma4(ho[r][c], wo[c], hv[r]);
            }
#pragma unroll
          for (int r = 0; r < ROWS; ++r) hv[r] = hv_n[r];
#pragma unroll
          for (int c = 0; c < 2; ++c) { wi[c] = wi_n[c]; wg[c] = wg_n[c]; wo[c] = wo_n[c]; }
        }
      }
      __syncthreads();                    // all reads of sha/shb complete
#pragma unroll
      for (int r = 0; r < ROWS; ++r)
#pragma unroll
        for (int c = 0; c < 2; ++c) {
          const int col = j + c * 256;
          const float iv = __fadd_rn(__fadd_rn(xi[r][c], hi[r][c]), bc1i[c]);
          const float gv = __fadd_rn(__fadd_rn(xg[r][c], hg[r][c]), bc1g[c]);
          const float ov = __fadd_rn(__fadd_rn(xo[r][c], ho[r][c]), bc1o[c]);
          const float cc = __fmul_rn(xla_sigmoid(iv), xla_tanh(gv));
          shb[r][col] = __fmul_rn(xla_sigmoid(ov), xla_tanh(cc));
        }
      __syncthreads();                    // shb now holds hb'
    }

    // ---- logits + gumbel ----
    {
      float lg[ROWS][2];
#pragma unroll
      for (int r = 0; r < ROWS; ++r) { lg[r][0] = 0.0f; lg[r][1] = 0.0f; }
      float4 wl[2], hv[ROWS];
      wl[0] = g_plo[j]; wl[1] = g_plo[j + 256];
#pragma unroll
      for (int r = 0; r < ROWS; ++r) hv[r] = *(const float4*)&shb[r][0];
#pragma unroll 1
      for (int k4 = 0; k4 < 128; ++k4) {
        const int nx = (k4 + 1) * 512;
        float4 wl_n[2], hv_n[ROWS];
#pragma unroll
        for (int r = 0; r < ROWS; ++r)
          hv_n[r] = *(const float4*)&shb[r][(k4 + 1) * 4];
        wl_n[0] = g_plo[nx + j]; wl_n[1] = g_plo[nx + j + 256];
#pragma unroll
        for (int r = 0; r < ROWS; ++r) {
          lg[r][0] = fma4(lg[r][0], wl[0], hv[r]);
          lg[r][1] = fma4(lg[r][1], wl[1], hv[r]);
        }
#pragma unroll
        for (int r = 0; r < ROWS; ++r) hv[r] = hv_n[r];
        wl[0] = wl_n[0]; wl[1] = wl_n[1];
      }
#pragma unroll
      for (int r = 0; r < ROWS; ++r)
#pragma unroll
        for (int c = 0; c < 2; ++c) {
          const int col = j + c * 256;
          const uint32_t cnt = (uint32_t)((b0 + r) * 512 + col);
          uint32_t o0, o1;
          threefry2x32(k0, k1, 0u, cnt, o0, o1);
          sx[r][col] = __fadd_rn(gumbel_from_bits(o0 ^ o1), __fadd_rn(lg[r][c], ob[c]));
        }
      __syncthreads();
    }

    // ---- per-row argmax: 4 waves, 2 rows each, first-index tiebreak ----
    {
      const int w = j >> 6, lane = j & 63;
#pragma unroll
      for (int rr = 0; rr < 2; ++rr) {
        const int r = w * 2 + rr;
        float bv = -3.402823466e38f;
        int bi = 0;
#pragma unroll
        for (int i = 0; i < 8; ++i) {
          const int v = i * 64 + lane;
          const float x = sx[r][v];
          if (x > bv) { bv = x; bi = v; }
        }
#pragma unroll
        for (int d = 1; d < 64; d <<= 1) {
          const float ov = __shfl_xor(bv, d, 64);
          const int oi = __shfl_xor(bi, d, 64);
          if (ov > bv || (ov == bv && oi < bi)) { bv = ov; bi = oi; }
        }
        if (lane == 0) {
          bi = bi < 0 ? 0 : (bi > 511 ? 511 : bi);
          stok[r] = bi;
          out[(size_t)(b0 + r) * 100 + t] = bi;
        }
      }
    }
    __syncthreads();
  }
}

// ---------------- host launcher ----------------
extern "C" void kernel_launch(void* const* d_in, const int* in_sizes, int n_in,
                              void* d_out, int out_size, void* d_ws, size_t ws_size,
                              hipStream_t stream) {
  (void)in_sizes; (void)n_in; (void)out_size; (void)d_ws; (void)ws_size;
  const float* P     = (const float*)d_in[0];
  const float* z     = (const float*)d_in[1];
  const float* pe_w1 = (const float*)d_in[2];
  const float* pe_b1 = (const float*)d_in[3];
  const float* pe_w2 = (const float*)d_in[4];
  const float* pe_b2 = (const float*)d_in[5];
  const float* fc_w  = (const float*)d_in[6];
  const float* fc_b  = (const float*)d_in[7];
  const float* wih0  = (const float*)d_in[8];
  const float* whh0  = (const float*)d_in[9];
  const float* bih0  = (const float*)d_in[10];
  const float* bhh0  = (const float*)d_in[11];
  const float* wih1  = (const float*)d_in[12];
  const float* whh1  = (const float*)d_in[13];
  const float* bih1  = (const float*)d_in[14];
  const float* bhh1  = (const float*)d_in[15];
  const float* out_w = (const float*)d_in[16];
  const float* out_b = (const float*)d_in[17];
  int* out = (int*)d_out;

  transpose_any<<<dim3(16, 64), 256, 0, stream>>>(wih0, 2048, 512, 0);
  transpose_any<<<dim3(32, 16), 256, 0, stream>>>(pe_w1, 512, 1024, 5);
  transpose_any<<<dim3(16, 8),  256, 0, stream>>>(pe_w2, 256, 512, 6);
  transpose_any<<<dim3(12, 16), 256, 0, stream>>>(fc_w, 512, 384, 7);

  pack3_kernel<<<768, 256, 0, stream>>>(whh0, 0);
  pack3_kernel<<<768, 256, 0, stream>>>(wih1, 1);
  pack3_kernel<<<768, 256, 0, stream>>>(whh1, 2);
  pack1_kernel<<<256, 256, 0, stream>>>(out_w, 3);

  pe1_kernel<<<4096, 512, 0, stream>>>(P, pe_b1);
  pe2_kernel<<<4096, 256, 0, stream>>>(pe_b2);
  h0_kernel<<<4096, 512, 0, stream>>>(z, fc_b);

  rnn_kernel<<<512, 256, 0, stream>>>(bih0, bhh0, bih1, bhh1, out_b, out);
}